// Round 11
// baseline (225.249 us; speedup 1.0000x reference)
//
#include <hip/hip_runtime.h>
#include <math.h>

#define DD 128          // embed dim
#define DEG 16          // neighbors
#define TM 32           // node tile per block (grid = ceil(50000/32) = 1563)
#define LDST 136        // LDS row stride in f16
#define EPSV 1e-5f
#define PGRID 1024      // persistent blocks for the streaming prep kernel

typedef _Float16 half8_t __attribute__((ext_vector_type(8)));
typedef float    f32x4   __attribute__((ext_vector_type(4)));
typedef signed char c16v __attribute__((ext_vector_type(16)));

// fast tanh(n)/n, n >= EPSV.
__device__ __forceinline__ float fast_tanh_over(float n) {
    float e  = __expf(2.f * n);
    float th = 1.f - __fdividef(2.f, e + 1.f);
    return __fdividef(th, n);
}
// fast atanh(n)/n, n in [EPSV, 1-EPSV]
__device__ __forceinline__ float fast_atanh_over(float n) {
    float r = 0.5f * __logf(__fdividef(1.f + n, 1.f - n));
    return __fdividef(r, n);
}

// ---- prep: PERSISTENT grid-stride. Per-row int8 quant of x*mask^2 + W->f16
// transpose. Unchanged from R9/R10.
__global__ __launch_bounds__(256, 2) void prep(
    const float* __restrict__ x, const float* __restrict__ mask,
    signed char* __restrict__ x8, float* __restrict__ xsc, int nA,
    const float* __restrict__ Wp, const float* __restrict__ Wn,
    _Float16* __restrict__ WT)
{
    if ((int)blockIdx.x < PGRID) {
        const int rr  = threadIdx.x >> 4;
        const int c16 = threadIdx.x & 15;
        for (int tb = blockIdx.x; tb < nA; tb += PGRID) {
            const int r = tb * 16 + rr;
            float m  = mask[r];
            float m2 = m * m;
            const float4* xp = (const float4*)(x + (size_t)r * DD + c16 * 8);
            float4 a = xp[0], b = xp[1];
            float v[8] = {a.x*m2, a.y*m2, a.z*m2, a.w*m2, b.x*m2, b.y*m2, b.z*m2, b.w*m2};
            float mx = 0.f;
            #pragma unroll
            for (int c = 0; c < 8; ++c) mx = fmaxf(mx, fabsf(v[c]));
            mx = fmaxf(mx, __shfl_xor(mx, 1));
            mx = fmaxf(mx, __shfl_xor(mx, 2));
            mx = fmaxf(mx, __shfl_xor(mx, 4));
            mx = fmaxf(mx, __shfl_xor(mx, 8));
            float qs = __fdividef(127.f, fmaxf(mx, 1e-20f));
            int q[8];
            #pragma unroll
            for (int c = 0; c < 8; ++c) q[c] = __float2int_rn(v[c] * qs);
            unsigned lo = (q[0]&255) | ((q[1]&255)<<8) | ((q[2]&255)<<16) | ((unsigned)(q[3]&255)<<24);
            unsigned hi = (q[4]&255) | ((q[5]&255)<<8) | ((q[6]&255)<<16) | ((unsigned)(q[7]&255)<<24);
            *(uint2*)(x8 + (size_t)r * DD + c16 * 8) = make_uint2(lo, hi);
            if (c16 == 0) xsc[r] = mx * (1.f / 127.f);
        }
    } else {
        int bid   = blockIdx.x - PGRID;    // 0..31
        int mat   = bid >> 3;              // 0..3: [l0p, l0n, l1p, l1n]
        int chunk = bid & 7;
        int l = mat >> 1, rel = mat & 1;
        const float* __restrict__ src = (rel ? Wn : Wp) + (size_t)l * DD * DD;
        _Float16* __restrict__ dst = WT + (size_t)mat * DD * DD;
        for (int o = chunk * 2048 + threadIdx.x; o < chunk * 2048 + 2048; o += 256) {
            int nn = o >> 7, kk = o & 127;
            dst[o] = (_Float16)src[kk * DD + nn];   // WT[n][k] (transposed)
        }
    }
}

// ---- fused GNN layer: R7/R10 int8 body, TM=32 / 512 threads / 1563 blocks.
// H-CP test: every ~3125-block dispatch measured 50-62us regardless of
// content (incl. R8's trivially-dense gemm_ep at 50us, 60% occ) -> suspected
// workgroup-dispatch rate cap ~60 WG/us. Halve the block count, double the
// block, keep the per-wave structure identical. launch_bounds(512,2) keeps
// the ~72-reg schedule (R5's spill came from the (512,8) VGPR clamp).
__global__ __launch_bounds__(512, 2) void fused_layer(
    const signed char* __restrict__ src8,        // int8, per-row scaled
    const float* __restrict__ sscale,            // per-row scale (rowmax/127)
    const int*   __restrict__ adj, const float* __restrict__ wgt,
    const float* __restrict__ mask,
    const _Float16* __restrict__ WTp, const _Float16* __restrict__ WTn,
    float* __restrict__ dst_f32,
    signed char* __restrict__ dst8, float* __restrict__ dst_scale,
    int n, int apply_logmap)
{
    __shared__ __align__(16) _Float16 aggP[TM][LDST];   // 8.5 KB
    __shared__ __align__(16) _Float16 aggN[TM][LDST];   // 8.5 KB
    __shared__ int   eidxS[TM][DEG];                     // 2 KB
    __shared__ float ewgtS[TM][DEG];                     // 2 KB (weight * src row-scale)
    __shared__ float msh[TM];
    __shared__ float partA[2][4][TM/2];                  // [row-tile][col-pair][row]
    __shared__ float partB[2][4][TM/2];
    __shared__ float partC[2][4][TM/2];

    const int row0 = blockIdx.x * TM;
    const int tid  = threadIdx.x;

    // ---- phase 0: stage adjacency, folded weights, mask (1 dword/thread) ----
    {
        const int nd = tid >> 4, eg = tid & 15;
        const int rowg = row0 + nd;
        int   av = 0;
        float wv = 0.f;
        if (rowg < n) {
            av = adj[(size_t)rowg * DEG + eg];
            wv = wgt[(size_t)rowg * DEG + eg];
        }
        eidxS[nd][eg] = av;
        ewgtS[nd][eg] = wv * sscale[av];       // sign preserved; av=0 safe
        if (tid < TM) msh[tid] = (row0 + tid < n) ? mask[row0 + tid] : 0.f;
    }
    __syncthreads();

    // ---- phase 1: gather-aggregate. 8 dwordx4 gathers/wave (8 lanes/row) ----
    const int w    = tid >> 6;                      // wave 0..7
    const int l64  = tid & 63;
    const int node = w * 4 + (l64 >> 4);            // 4 nodes per wave -> 0..31
    const int e    = (l64 >> 3) & 1;                // edge parity within instr
    const int g    = l64 & 7;                       // 16-byte column group

    int   idxl[8];
    float wl[8];
    #pragma unroll
    for (int j = 0; j < 8; ++j) {
        idxl[j] = eidxS[node][2 * j + e];
        wl[j]   = ewgtS[node][2 * j + e];
    }

    float aP[16], aN[16];
    #pragma unroll
    for (int c = 0; c < 16; ++c) { aP[c] = 0.f; aN[c] = 0.f; }
    const signed char* __restrict__ srcg = src8 + g * 16;
    #pragma unroll
    for (int j = 0; j < 8; ++j) {
        c16v v = *(const c16v*)(srcg + ((size_t)idxl[j] << 7));
        float wp = fmaxf(wl[j], 0.f);
        float wn = fmaxf(-wl[j], 0.f);
        #pragma unroll
        for (int c = 0; c < 16; ++c) {
            float f = (float)v[c];
            aP[c] += wp * f;
            aN[c] += wn * f;
        }
    }
    // merge edge parities: lane^8 covers the SAME 16 columns, other parity.
    // Keep own half, SEND the opposite half (R7-verified).
    {
        half8_t hP, hN;
        #pragma unroll
        for (int c = 0; c < 8; ++c) {
            float ownP  = e ? aP[8 + c] : aP[c];
            float sendP = e ? aP[c]     : aP[8 + c];
            float ownN  = e ? aN[8 + c] : aN[c];
            float sendN = e ? aN[c]     : aN[8 + c];
            hP[c] = (_Float16)(ownP + __shfl_xor(sendP, 8));
            hN[c] = (_Float16)(ownN + __shfl_xor(sendN, 8));
        }
        *(half8_t*)&aggP[node][g * 16 + e * 8] = hP;
        *(half8_t*)&aggN[node][g * 16 + e * 8] = hN;
    }
    __syncthreads();

    // ---- phase 2: MFMA. 8 waves = 2 row-tiles x 4 col-pairs ----
    const int nt   = w >> 2;         // row-tile: rows nt*16 .. nt*16+15
    const int nb2  = w & 3;          // col-pair: n-blocks {nb2*2, nb2*2+1}
    const int l15  = l64 & 15;
    const int quad = l64 >> 4;

    half8_t aPf[4], aNf[4];          // A[m=l15][k=kb*32+quad*8+j]
    #pragma unroll
    for (int kb = 0; kb < 4; ++kb) {
        aPf[kb] = *(const half8_t*)&aggP[nt * 16 + l15][kb * 32 + quad * 8];
        aNf[kb] = *(const half8_t*)&aggN[nt * 16 + l15][kb * 32 + quad * 8];
    }

    f32x4 acc[2];
    acc[0] = (f32x4){0.f, 0.f, 0.f, 0.f};
    acc[1] = (f32x4){0.f, 0.f, 0.f, 0.f};
    #pragma unroll
    for (int t = 0; t < 2; ++t) {
        const int nb = nb2 * 2 + t;
        const _Float16* bp = WTp + (size_t)(nb * 16 + l15) * DD + quad * 8;
        const _Float16* bn = WTn + (size_t)(nb * 16 + l15) * DD + quad * 8;
        #pragma unroll
        for (int kb = 0; kb < 4; ++kb) {
            acc[t] = __builtin_amdgcn_mfma_f32_16x16x32_f16(
                aPf[kb], *(const half8_t*)(bp + kb * 32), acc[t], 0, 0, 0);
            acc[t] = __builtin_amdgcn_mfma_f32_16x16x32_f16(
                aNf[kb], *(const half8_t*)(bn + kb * 32), acc[t], 0, 0, 0);
        }
    }

    // ---- phase 3: epilogue. C/D: local row = nt*16 + quad*4+r,
    //      cols nb2*32 + {l15, 16+l15} ----
    float cv0[4], cv1[4], mr[4];
    #pragma unroll
    for (int r = 0; r < 4; ++r) {
        const int rl   = quad * 4 + r;           // row within 16-row tile
        const int lrow = nt * 16 + rl;
        float m = msh[lrow];                     // 0 for rows >= n
        mr[r] = m;
        float c0 = acc[0][r] * m, c1 = acc[1][r] * m;
        cv0[r] = c0; cv1[r] = c1;
        float p = c0 * c0 + c1 * c1;
        p += __shfl_xor(p, 1); p += __shfl_xor(p, 2);
        p += __shfl_xor(p, 4); p += __shfl_xor(p, 8);   // within 16-lane group
        if (l15 == 0) partA[nt][nb2][rl] = p;
    }
    __syncthreads();

    float x0[4], x1[4];
    #pragma unroll
    for (int r = 0; r < 4; ++r) {
        const int rl = quad * 4 + r;
        float c2 = partA[nt][0][rl] + partA[nt][1][rl] + partA[nt][2][rl] + partA[nt][3][rl];
        float nc = fmaxf(sqrtf(c2), EPSV);
        float sc = fast_tanh_over(nc);
        float m  = mr[r];
        float t0 = fmaxf(cv0[r] * sc * m, 0.f) * m;      // expmap*m, relu, *m
        float t1 = fmaxf(cv1[r] * sc * m, 0.f) * m;
        x0[r] = t0; x1[r] = t1;
        if (apply_logmap) {                               // uniform branch
            float p = t0 * t0 + t1 * t1;
            p += __shfl_xor(p, 1); p += __shfl_xor(p, 2);
            p += __shfl_xor(p, 4); p += __shfl_xor(p, 8);
            if (l15 == 0) partB[nt][nb2][rl] = p;
        }
    }

    if (apply_logmap) {
        __syncthreads();
        // y = logmap(x)*mask^2; compute + per-row max partials
        float y0r[4], y1r[4];
        #pragma unroll
        for (int r = 0; r < 4; ++r) {
            const int rl = quad * 4 + r;
            float s2  = partB[nt][0][rl] + partB[nt][1][rl] + partB[nt][2][rl] + partB[nt][3][rl];
            float nc2 = fminf(fmaxf(sqrtf(s2), EPSV), 1.f - EPSV);
            float f = fast_atanh_over(nc2) * mr[r] * mr[r];
            float y0 = x0[r] * f, y1 = x1[r] * f;
            y0r[r] = y0; y1r[r] = y1;
            float mm = fmaxf(fabsf(y0), fabsf(y1));
            mm = fmaxf(mm, __shfl_xor(mm, 1));
            mm = fmaxf(mm, __shfl_xor(mm, 2));
            mm = fmaxf(mm, __shfl_xor(mm, 4));
            mm = fmaxf(mm, __shfl_xor(mm, 8));
            if (l15 == 0) partC[nt][nb2][rl] = mm;
        }
        __syncthreads();
        #pragma unroll
        for (int r = 0; r < 4; ++r) {
            const int rl  = quad * 4 + r;
            const int row = row0 + nt * 16 + rl;
            if (row >= n) continue;
            float rmax = fmaxf(fmaxf(partC[nt][0][rl], partC[nt][1][rl]),
                               fmaxf(partC[nt][2][rl], partC[nt][3][rl]));
            float qs = __fdividef(127.f, fmaxf(rmax, 1e-20f));
            int q0 = __float2int_rn(y0r[r] * qs);
            int q1 = __float2int_rn(y1r[r] * qs);
            signed char* drow = dst8 + (size_t)row * DD + nb2 * 32 + l15;
            drow[0]  = (signed char)q0;
            drow[16] = (signed char)q1;
            if (nb2 == 0 && l15 == 0) dst_scale[row] = rmax * (1.f / 127.f);
        }
    } else {
        #pragma unroll
        for (int r = 0; r < 4; ++r) {
            const int rl  = quad * 4 + r;
            const int row = row0 + nt * 16 + rl;
            if (row >= n) continue;
            float* drow = dst_f32 + (size_t)row * DD + nb2 * 32 + l15;
            drow[0]  = x0[r];
            drow[16] = x1[r];
        }
    }
}

extern "C" void kernel_launch(void* const* d_in, const int* in_sizes, int n_in,
                              void* d_out, int out_size, void* d_ws, size_t ws_size,
                              hipStream_t stream)
{
    const float* node_repr = (const float*)d_in[0];
    const int*   adj       = (const int*)  d_in[1];
    const float* weight    = (const float*)d_in[2];
    const float* mask      = (const float*)d_in[3];
    const float* W_pos     = (const float*)d_in[4];   // [L,128,128]
    const float* W_neg     = (const float*)d_in[5];

    const int n = in_sizes[0] / DD;                   // 50000

    // workspace: x8 | y8 | xsc | ysc | WT
    signed char* x8  = (signed char*)d_ws;                 // n*128 B
    signed char* y8  = x8 + (size_t)n * DD;                // n*128 B
    float*       xsc = (float*)(y8 + (size_t)n * DD);      // n f32
    float*       ysc = xsc + n;                            // n f32
    _Float16*    WT  = (_Float16*)(ysc + n);               // 4*128*128 f16

    const int nA = n / 16;                                 // 3125 row-quant tiles
    prep<<<PGRID + 32, 256, 0, stream>>>(node_repr, mask, x8, xsc, nA,
                                         W_pos, W_neg, WT);

    dim3 grid((n + TM - 1) / TM);                          // 1563 blocks of 512
    // layer 0: gather x8, write y8 (int8 row-scaled) + ysc
    fused_layer<<<grid, 512, 0, stream>>>(x8, xsc, adj, weight, mask,
                                          WT + 0 * DD * DD, WT + 1 * DD * DD,
                                          nullptr, y8, ysc, n, 1);
    // layer 1: gather y8, write f32 output
    fused_layer<<<grid, 512, 0, stream>>>(y8, ysc, adj, weight, mask,
                                          WT + 2 * DD * DD, WT + 3 * DD * DD,
                                          (float*)d_out, nullptr, nullptr, n, 0);
}

// Round 12
// 202.181 us; speedup vs baseline: 1.1141x; 1.1141x over previous
//
#include <hip/hip_runtime.h>
#include <math.h>

#define DD 128          // embed dim
#define DEG 16          // neighbors
#define TM 16           // node tile per block (grid = 50000/16 = 3125 exactly)
#define LDST 136        // LDS row stride in f16
#define EPSV 1e-5f

typedef _Float16 half8_t __attribute__((ext_vector_type(8)));
typedef float    f32x4   __attribute__((ext_vector_type(4)));
typedef signed char c16v __attribute__((ext_vector_type(16)));

// fast tanh(n)/n, n >= EPSV.
__device__ __forceinline__ float fast_tanh_over(float n) {
    float e  = __expf(2.f * n);
    float th = 1.f - __fdividef(2.f, e + 1.f);
    return __fdividef(th, n);
}
// fast atanh(n)/n, n in [EPSV, 1-EPSV]
__device__ __forceinline__ float fast_atanh_over(float n) {
    float r = 0.5f * __logf(__fdividef(1.f + n, 1.f - n));
    return __fdividef(r, n);
}

// ---- prepW: W->f16 transpose ONLY (32 blocks). R12: the old prep's x-quant
// pass cost ~60us -- a trivial streaming kernel at 427 GB/s, invariant to
// persistence (R7 vs R10). Its unique feature: FIRST-TOUCH of the cold 25.6MB
// input. Fix: layer 0 gathers raw f32 x directly, so the cold reads overlap
// the gather phase's proven latency slack; prep keeps only the 256KB W work.
__global__ void prepW(const float* __restrict__ Wp, const float* __restrict__ Wn,
                      _Float16* __restrict__ WT)
{
    int bid   = blockIdx.x;            // 0..31
    int mat   = bid >> 3;              // 0..3: [l0p, l0n, l1p, l1n]
    int chunk = bid & 7;
    int l = mat >> 1, rel = mat & 1;
    const float* __restrict__ src = (rel ? Wn : Wp) + (size_t)l * DD * DD;
    _Float16* __restrict__ dst = WT + (size_t)mat * DD * DD;
    for (int o = chunk * 2048 + threadIdx.x; o < chunk * 2048 + 2048; o += 256) {
        int nn = o >> 7, kk = o & 127;
        dst[o] = (_Float16)src[kk * DD + nn];   // WT[n][k] (transposed)
    }
}

// ---- layer 0: f32 gather (R0 gather geometry, R7 MFMA/epilogue).
// msg_s = m_s^2 * (x_s @ W) -> fold m_av^2 into the edge weight (staged
// scattered dword, same cost as R7's sscale[av]). Output: y8 + ysc (int8
// row-scaled logmap(y)*mask^2), as R7's apply_logmap path.
__global__ __launch_bounds__(256, 2) void fused_l0_f32(
    const float* __restrict__ xsrc,              // raw f32 node_repr [n][128]
    const int*   __restrict__ adj, const float* __restrict__ wgt,
    const float* __restrict__ mask,
    const _Float16* __restrict__ WTp, const _Float16* __restrict__ WTn,
    signed char* __restrict__ dst8, float* __restrict__ dst_scale,
    int n)
{
    __shared__ __align__(16) _Float16 aggP[TM][LDST];   // 4.25 KB
    __shared__ __align__(16) _Float16 aggN[TM][LDST];   // 4.25 KB
    __shared__ int   eidxS[TM][DEG];                     // 1 KB
    __shared__ float ewgtS[TM][DEG];                     // 1 KB (w * mask[av]^2)
    __shared__ float msh[TM];
    __shared__ float partA[4][TM];
    __shared__ float partB[4][TM];
    __shared__ float partC[4][TM];

    const int row0 = blockIdx.x * TM;
    const int tid  = threadIdx.x;

    // ---- phase 0: stage adjacency + folded weights + mask ----
    {
        const int nd = tid >> 4, eg = tid & 15;
        int   av = adj[(size_t)(row0 + nd) * DEG + eg];
        float wv = wgt[(size_t)(row0 + nd) * DEG + eg];
        float mv = mask[av];                   // scattered dword (as sscale was)
        eidxS[nd][eg] = av;
        ewgtS[nd][eg] = wv * mv * mv;          // sign preserved
        if (tid < TM) msh[tid] = mask[row0 + tid];
    }
    __syncthreads();

    // ---- phase 1: f32 gather-aggregate. 16 nodes x 16 lanes; lane covers
    // cols [l16*8, l16*8+8) via 2 float4 per edge (32 gathers/lane; R2 proved
    // gather-instruction count is not the limiter).
    const int qw  = tid >> 4;          // node row 0..15
    const int l16 = tid & 15;
    float aP[8] = {0.f,0.f,0.f,0.f,0.f,0.f,0.f,0.f};
    float aN[8] = {0.f,0.f,0.f,0.f,0.f,0.f,0.f,0.f};
    {
        const float* __restrict__ srcb = xsrc + l16 * 8;
        #pragma unroll
        for (int j = 0; j < 16; ++j) {
            const int   idx = eidxS[qw][j];
            const float w   = ewgtS[qw][j];
            const float* rp = srcb + (size_t)idx * DD;
            float4 v0 = ((const float4*)rp)[0];
            float4 v1 = ((const float4*)rp)[1];
            float wp = fmaxf(w, 0.f);
            float wn = fmaxf(-w, 0.f);
            float f0[8] = {v0.x, v0.y, v0.z, v0.w, v1.x, v1.y, v1.z, v1.w};
            #pragma unroll
            for (int c = 0; c < 8; ++c) {
                aP[c] += wp * f0[c];
                aN[c] += wn * f0[c];
            }
        }
    }
    {
        half8_t hP, hN;
        #pragma unroll
        for (int c = 0; c < 8; ++c) { hP[c] = (_Float16)aP[c]; hN[c] = (_Float16)aN[c]; }
        *(half8_t*)&aggP[qw][l16 * 8] = hP;
        *(half8_t*)&aggN[qw][l16 * 8] = hN;
    }
    __syncthreads();

    // ---- phase 2: MFMA. 4 waves split the 8 n-blocks (2 each) ----
    const int wv2  = tid >> 6;
    const int l64  = tid & 63;
    const int l15  = l64 & 15;
    const int quad = l64 >> 4;

    half8_t aPf[4], aNf[4];
    #pragma unroll
    for (int kb = 0; kb < 4; ++kb) {
        aPf[kb] = *(const half8_t*)&aggP[l15][kb * 32 + quad * 8];
        aNf[kb] = *(const half8_t*)&aggN[l15][kb * 32 + quad * 8];
    }

    f32x4 acc[2];
    acc[0] = (f32x4){0.f, 0.f, 0.f, 0.f};
    acc[1] = (f32x4){0.f, 0.f, 0.f, 0.f};
    #pragma unroll
    for (int t = 0; t < 2; ++t) {
        const int nb = wv2 * 2 + t;
        const _Float16* bp = WTp + (size_t)(nb * 16 + l15) * DD + quad * 8;
        const _Float16* bn = WTn + (size_t)(nb * 16 + l15) * DD + quad * 8;
        #pragma unroll
        for (int kb = 0; kb < 4; ++kb) {
            acc[t] = __builtin_amdgcn_mfma_f32_16x16x32_f16(
                aPf[kb], *(const half8_t*)(bp + kb * 32), acc[t], 0, 0, 0);
            acc[t] = __builtin_amdgcn_mfma_f32_16x16x32_f16(
                aNf[kb], *(const half8_t*)(bn + kb * 32), acc[t], 0, 0, 0);
        }
    }

    // ---- phase 3: epilogue (expmap, relu, logmap, int8 y output) ----
    float cv0[4], cv1[4], mr[4];
    #pragma unroll
    for (int r = 0; r < 4; ++r) {
        const int rl  = quad * 4 + r;
        const int row = row0 + rl;
        float m = (row < n) ? msh[rl] : 0.f;
        mr[r] = m;
        float c0 = acc[0][r] * m, c1 = acc[1][r] * m;
        cv0[r] = c0; cv1[r] = c1;
        float p = c0 * c0 + c1 * c1;
        p += __shfl_xor(p, 1); p += __shfl_xor(p, 2);
        p += __shfl_xor(p, 4); p += __shfl_xor(p, 8);
        if (l15 == 0) partA[wv2][rl] = p;
    }
    __syncthreads();

    float x0[4], x1[4];
    #pragma unroll
    for (int r = 0; r < 4; ++r) {
        const int rl = quad * 4 + r;
        float c2 = partA[0][rl] + partA[1][rl] + partA[2][rl] + partA[3][rl];
        float nc = fmaxf(sqrtf(c2), EPSV);
        float sc = fast_tanh_over(nc);
        float m  = mr[r];
        float t0 = fmaxf(cv0[r] * sc * m, 0.f) * m;
        float t1 = fmaxf(cv1[r] * sc * m, 0.f) * m;
        x0[r] = t0; x1[r] = t1;
        float p = t0 * t0 + t1 * t1;
        p += __shfl_xor(p, 1); p += __shfl_xor(p, 2);
        p += __shfl_xor(p, 4); p += __shfl_xor(p, 8);
        if (l15 == 0) partB[wv2][rl] = p;
    }
    __syncthreads();

    float y0r[4], y1r[4];
    #pragma unroll
    for (int r = 0; r < 4; ++r) {
        const int rl = quad * 4 + r;
        float s2  = partB[0][rl] + partB[1][rl] + partB[2][rl] + partB[3][rl];
        float nc2 = fminf(fmaxf(sqrtf(s2), EPSV), 1.f - EPSV);
        float f = fast_atanh_over(nc2) * mr[r] * mr[r];
        float y0 = x0[r] * f, y1 = x1[r] * f;
        y0r[r] = y0; y1r[r] = y1;
        float mm = fmaxf(fabsf(y0), fabsf(y1));
        mm = fmaxf(mm, __shfl_xor(mm, 1));
        mm = fmaxf(mm, __shfl_xor(mm, 2));
        mm = fmaxf(mm, __shfl_xor(mm, 4));
        mm = fmaxf(mm, __shfl_xor(mm, 8));
        if (l15 == 0) partC[wv2][rl] = mm;
    }
    __syncthreads();
    #pragma unroll
    for (int r = 0; r < 4; ++r) {
        const int rl  = quad * 4 + r;
        const int row = row0 + rl;
        if (row >= n) continue;
        float rmax = fmaxf(fmaxf(partC[0][rl], partC[1][rl]),
                           fmaxf(partC[2][rl], partC[3][rl]));
        float qs = __fdividef(127.f, fmaxf(rmax, 1e-20f));
        int q0 = __float2int_rn(y0r[r] * qs);
        int q1 = __float2int_rn(y1r[r] * qs);
        signed char* drow = dst8 + (size_t)row * DD + wv2 * 32 + l15;
        drow[0]  = (signed char)q0;
        drow[16] = (signed char)q1;
        if (wv2 == 0 && l15 == 0) dst_scale[row] = rmax * (1.f / 127.f);
    }
}

// ---- layer 1: EXACT R7/R10 int8 kernel (57.5us measured), f32 output path.
__global__ __launch_bounds__(256, 2) void fused_l1_i8(
    const signed char* __restrict__ src8,        // int8, per-row scaled
    const float* __restrict__ sscale,            // per-row scale (rowmax/127)
    const int*   __restrict__ adj, const float* __restrict__ wgt,
    const float* __restrict__ mask,
    const _Float16* __restrict__ WTp, const _Float16* __restrict__ WTn,
    float* __restrict__ dst_f32, int n)
{
    __shared__ __align__(16) _Float16 aggP[TM][LDST];
    __shared__ __align__(16) _Float16 aggN[TM][LDST];
    __shared__ int   eidxS[TM][DEG];
    __shared__ float ewgtS[TM][DEG];
    __shared__ float msh[TM];
    __shared__ float partA[4][TM];

    const int row0 = blockIdx.x * TM;
    const int tid  = threadIdx.x;

    // ---- phase 0 ----
    {
        const int nd = tid >> 4, eg = tid & 15;
        int   av = adj[(size_t)(row0 + nd) * DEG + eg];
        float wv = wgt[(size_t)(row0 + nd) * DEG + eg];
        float sv = sscale[av];
        eidxS[nd][eg] = av;
        ewgtS[nd][eg] = wv * sv;
        if (tid < TM) msh[tid] = mask[row0 + tid];
    }
    __syncthreads();

    // ---- phase 1: int8 gather, 8 dwordx4/wave ----
    const int l64  = tid & 63;
    const int node = (tid >> 6) * 4 + (l64 >> 4);
    const int e    = (l64 >> 3) & 1;
    const int g    = l64 & 7;

    int   idxl[8];
    float wl[8];
    #pragma unroll
    for (int j = 0; j < 8; ++j) {
        idxl[j] = eidxS[node][2 * j + e];
        wl[j]   = ewgtS[node][2 * j + e];
    }

    float aP[16], aN[16];
    #pragma unroll
    for (int c = 0; c < 16; ++c) { aP[c] = 0.f; aN[c] = 0.f; }
    const signed char* __restrict__ srcg = src8 + g * 16;
    #pragma unroll
    for (int j = 0; j < 8; ++j) {
        c16v v = *(const c16v*)(srcg + ((size_t)idxl[j] << 7));
        float wp = fmaxf(wl[j], 0.f);
        float wn = fmaxf(-wl[j], 0.f);
        #pragma unroll
        for (int c = 0; c < 16; ++c) {
            float f = (float)v[c];
            aP[c] += wp * f;
            aN[c] += wn * f;
        }
    }
    // parity merge (R7-verified): keep own half, send opposite half
    {
        half8_t hP, hN;
        #pragma unroll
        for (int c = 0; c < 8; ++c) {
            float ownP  = e ? aP[8 + c] : aP[c];
            float sendP = e ? aP[c]     : aP[8 + c];
            float ownN  = e ? aN[8 + c] : aN[c];
            float sendN = e ? aN[c]     : aN[8 + c];
            hP[c] = (_Float16)(ownP + __shfl_xor(sendP, 8));
            hN[c] = (_Float16)(ownN + __shfl_xor(sendN, 8));
        }
        *(half8_t*)&aggP[node][g * 16 + e * 8] = hP;
        *(half8_t*)&aggN[node][g * 16 + e * 8] = hN;
    }
    __syncthreads();

    // ---- phase 2: MFMA ----
    const int wv2  = tid >> 6;
    const int l15  = l64 & 15;
    const int quad = l64 >> 4;

    half8_t aPf[4], aNf[4];
    #pragma unroll
    for (int kb = 0; kb < 4; ++kb) {
        aPf[kb] = *(const half8_t*)&aggP[l15][kb * 32 + quad * 8];
        aNf[kb] = *(const half8_t*)&aggN[l15][kb * 32 + quad * 8];
    }

    f32x4 acc[2];
    acc[0] = (f32x4){0.f, 0.f, 0.f, 0.f};
    acc[1] = (f32x4){0.f, 0.f, 0.f, 0.f};
    #pragma unroll
    for (int t = 0; t < 2; ++t) {
        const int nb = wv2 * 2 + t;
        const _Float16* bp = WTp + (size_t)(nb * 16 + l15) * DD + quad * 8;
        const _Float16* bn = WTn + (size_t)(nb * 16 + l15) * DD + quad * 8;
        #pragma unroll
        for (int kb = 0; kb < 4; ++kb) {
            acc[t] = __builtin_amdgcn_mfma_f32_16x16x32_f16(
                aPf[kb], *(const half8_t*)(bp + kb * 32), acc[t], 0, 0, 0);
            acc[t] = __builtin_amdgcn_mfma_f32_16x16x32_f16(
                aNf[kb], *(const half8_t*)(bn + kb * 32), acc[t], 0, 0, 0);
        }
    }

    // ---- phase 3: epilogue (expmap, relu, f32 out) ----
    float cv0[4], cv1[4], mr[4];
    #pragma unroll
    for (int r = 0; r < 4; ++r) {
        const int rl  = quad * 4 + r;
        const int row = row0 + rl;
        float m = (row < n) ? msh[rl] : 0.f;
        mr[r] = m;
        float c0 = acc[0][r] * m, c1 = acc[1][r] * m;
        cv0[r] = c0; cv1[r] = c1;
        float p = c0 * c0 + c1 * c1;
        p += __shfl_xor(p, 1); p += __shfl_xor(p, 2);
        p += __shfl_xor(p, 4); p += __shfl_xor(p, 8);
        if (l15 == 0) partA[wv2][rl] = p;
    }
    __syncthreads();

    #pragma unroll
    for (int r = 0; r < 4; ++r) {
        const int rl  = quad * 4 + r;
        const int row = row0 + rl;
        if (row >= n) continue;
        float c2 = partA[0][rl] + partA[1][rl] + partA[2][rl] + partA[3][rl];
        float nc = fmaxf(sqrtf(c2), EPSV);
        float sc = fast_tanh_over(nc);
        float m  = mr[r];
        float t0 = fmaxf(cv0[r] * sc * m, 0.f) * m;
        float t1 = fmaxf(cv1[r] * sc * m, 0.f) * m;
        float* drow = dst_f32 + (size_t)row * DD + wv2 * 32 + l15;
        drow[0]  = t0;
        drow[16] = t1;
    }
}

extern "C" void kernel_launch(void* const* d_in, const int* in_sizes, int n_in,
                              void* d_out, int out_size, void* d_ws, size_t ws_size,
                              hipStream_t stream)
{
    const float* node_repr = (const float*)d_in[0];
    const int*   adj       = (const int*)  d_in[1];
    const float* weight    = (const float*)d_in[2];
    const float* mask      = (const float*)d_in[3];
    const float* W_pos     = (const float*)d_in[4];   // [L,128,128]
    const float* W_neg     = (const float*)d_in[5];

    const int n = in_sizes[0] / DD;                   // 50000

    // workspace: y8 | ysc | WT
    signed char* y8  = (signed char*)d_ws;                 // n*128 B
    float*       ysc = (float*)(y8 + (size_t)n * DD);      // n f32
    _Float16*    WT  = (_Float16*)(ysc + n);               // 4*128*128 f16

    prepW<<<32, 256, 0, stream>>>(W_pos, W_neg, WT);

    dim3 grid((n + TM - 1) / TM);                          // 3125 blocks of 256
    // layer 0: gather raw f32 x (cold reads overlap gather slack), write y8+ysc
    fused_l0_f32<<<grid, 256, 0, stream>>>(node_repr, adj, weight, mask,
                                           WT + 0 * DD * DD, WT + 1 * DD * DD,
                                           y8, ysc, n);
    // layer 1: int8 gather (R7-measured 57.5us), write f32 output
    fused_l1_i8<<<grid, 256, 0, stream>>>(y8, ysc, adj, weight, mask,
                                          WT + 2 * DD * DD, WT + 3 * DD * DD,
                                          (float*)d_out, n);
}

// Round 14
// 191.558 us; speedup vs baseline: 1.1759x; 1.0555x over previous
//
#include <hip/hip_runtime.h>
#include <math.h>

#define DD 128          // embed dim
#define DEG 16          // neighbors
#define TMG 16          // gather tile (3125 blocks exact)
#define TMZ 32          // z-gemm rows per block (1563 blocks)
#define LDST 136        // LDS row stride in f16
#define EPSV 1e-5f

typedef _Float16 half8_t __attribute__((ext_vector_type(8)));
typedef float    f32x4   __attribute__((ext_vector_type(4)));
typedef signed char c16v __attribute__((ext_vector_type(16)));

// fast tanh(n)/n, n >= EPSV.
__device__ __forceinline__ float fast_tanh_over(float n) {
    float e  = __expf(2.f * n);
    float th = 1.f - __fdividef(2.f, e + 1.f);
    return __fdividef(th, n);
}
// fast atanh(n)/n, n in [EPSV, 1-EPSV]
__device__ __forceinline__ float fast_atanh_over(float n) {
    float r = 0.5f * __logf(__fdividef(1.f + n, 1.f - n));
    return __fdividef(r, n);
}

// ---- prepW: W->f16 transpose (verified layout: WT[n][k]) ----
__global__ void prepW(const float* __restrict__ Wp, const float* __restrict__ Wn,
                      _Float16* __restrict__ WT)
{
    int bid   = blockIdx.x;            // 0..31
    int mat   = bid >> 3;              // 0..3: [l0p, l0n, l1p, l1n]
    int chunk = bid & 7;
    int l = mat >> 1, rel = mat & 1;
    const float* __restrict__ src = (rel ? Wn : Wp) + (size_t)l * DD * DD;
    _Float16* __restrict__ dst = WT + (size_t)mat * DD * DD;
    for (int o = chunk * 2048 + threadIdx.x; o < chunk * 2048 + 2048; o += 256) {
        int nn = o >> 7, kk = o & 127;
        dst[o] = (_Float16)src[kk * DD + nn];   // WT[n][k] (transposed)
    }
}

// ---- z_gemm: dense Z^rel = A @ W^rel for rel in {P,N}, int8 per-row output.
// R13 restructure (resubmitted R14 after infra failure; desk-checked):
// each edge is pos XOR neg, so combined = sum |w|*Z^sign[a]. Precomputing Z
// moves ALL MFMA+LDS+barrier machinery out of the scatter kernel into this
// dense streaming GEMM (which also absorbs the cold-x read).
// A = x*mask^2 (layer0, f32 in) or y (layer1, int8*ysc in). Wave w of 4:
// row-half w>>1, relation w&1; acc[8] covers all 128 cols (col=nb*16+l15,
// row=quad*4+r -- verified C/D layout).
__global__ __launch_bounds__(256, 2) void z_gemm(
    const float* __restrict__ xf32,          // layer0 input (else unused)
    const signed char* __restrict__ y8,      // layer1 input (else unused)
    const float* __restrict__ ysc,
    const float* __restrict__ mask,
    const _Float16* __restrict__ WTp, const _Float16* __restrict__ WTn,
    signed char* __restrict__ Z8,            // [2][n][128] (P then N)
    float* __restrict__ zscP, float* __restrict__ zscN,
    int n, int layer0)
{
    __shared__ __align__(16) _Float16 At[TMZ][LDST];    // 8.7 KB

    const int row0 = blockIdx.x * TMZ;
    const int tid  = threadIdx.x;

    // ---- stage A-tile: thread t covers row=t>>3, cols (t&7)*16..+16 ----
    {
        const int ar   = tid >> 3;
        const int ac   = (tid & 7) * 16;
        const int rowg = row0 + ar;
        _Float16 hv[16];
        if (rowg < n) {
            if (layer0) {
                float m = mask[rowg]; float m2 = m * m;
                const float4* xp = (const float4*)(xf32 + (size_t)rowg * DD + ac);
                #pragma unroll
                for (int q4 = 0; q4 < 4; ++q4) {
                    float4 v = xp[q4];
                    hv[q4*4+0] = (_Float16)(v.x*m2); hv[q4*4+1] = (_Float16)(v.y*m2);
                    hv[q4*4+2] = (_Float16)(v.z*m2); hv[q4*4+3] = (_Float16)(v.w*m2);
                }
            } else {
                float s = ysc[rowg];
                c16v v = *(const c16v*)(y8 + (size_t)rowg * DD + ac);
                #pragma unroll
                for (int c = 0; c < 16; ++c) hv[c] = (_Float16)((float)v[c] * s);
            }
        } else {
            #pragma unroll
            for (int c = 0; c < 16; ++c) hv[c] = (_Float16)0.f;
        }
        *(half8_t*)&At[ar][ac]     = *(half8_t*)&hv[0];
        *(half8_t*)&At[ar][ac + 8] = *(half8_t*)&hv[8];
    }
    __syncthreads();

    const int w    = tid >> 6;       // wave 0..3
    const int mt   = w >> 1;         // row half 0/1
    const int rel  = w & 1;          // 0=P, 1=N
    const int l64  = tid & 63;
    const int l15  = l64 & 15;
    const int quad = l64 >> 4;

    half8_t aF[4];                   // A[m=l15][k=kb*32+quad*8+j] (verified)
    #pragma unroll
    for (int kb = 0; kb < 4; ++kb)
        aF[kb] = *(const half8_t*)&At[mt * 16 + l15][kb * 32 + quad * 8];

    const _Float16* __restrict__ WT = rel ? WTn : WTp;
    f32x4 acc[8];
    #pragma unroll
    for (int nb = 0; nb < 8; ++nb) acc[nb] = (f32x4){0.f, 0.f, 0.f, 0.f};
    #pragma unroll
    for (int nb = 0; nb < 8; ++nb) {
        const _Float16* bp = WT + (size_t)(nb * 16 + l15) * DD + quad * 8;
        #pragma unroll
        for (int kb = 0; kb < 4; ++kb)
            acc[nb] = __builtin_amdgcn_mfma_f32_16x16x32_f16(
                aF[kb], *(const half8_t*)(bp + kb * 32), acc[nb], 0, 0, 0);
    }

    // ---- epilogue: per-row int8 quant, fully within-wave (no barriers) ----
    signed char* __restrict__ zb  = Z8 + (size_t)rel * n * DD;
    float*       __restrict__ zsc = rel ? zscN : zscP;
    #pragma unroll
    for (int r = 0; r < 4; ++r) {
        const int rowg = row0 + mt * 16 + quad * 4 + r;
        float mx = 0.f;
        #pragma unroll
        for (int nb = 0; nb < 8; ++nb) mx = fmaxf(mx, fabsf(acc[nb][r]));
        mx = fmaxf(mx, __shfl_xor(mx, 1));
        mx = fmaxf(mx, __shfl_xor(mx, 2));
        mx = fmaxf(mx, __shfl_xor(mx, 4));
        mx = fmaxf(mx, __shfl_xor(mx, 8));   // row-max across the 16-lane group
        if (rowg < n) {
            float qs = __fdividef(127.f, fmaxf(mx, 1e-20f));
            signed char* zr = zb + (size_t)rowg * DD + l15;
            #pragma unroll
            for (int nb = 0; nb < 8; ++nb)
                zr[nb * 16] = (signed char)__float2int_rn(acc[nb][r] * qs);
            if (l15 == 0) zsc[rowg] = mx * (1.f / 127.f);
        }
    }
}

// ---- gather_ep: pure gather + weighted-sum + epilogue. ONE barrier, zero
// MFMA, zero LDS roundtrip for data; all norms via 16-lane shuffles. This is
// the structure of the measured-fast kernels (gather_agg / l0_f32), with the
// GEMM commuted out. Gather bytes unchanged vs R7: 128 B/edge int8 (pos/neg
// row selected by weight sign; |w| * rowscale folded at staging).
__global__ __launch_bounds__(256, 2) void gather_ep(
    const signed char* __restrict__ Z8,      // [2][n][128]
    const float* __restrict__ zscP, const float* __restrict__ zscN,
    const int*   __restrict__ adj, const float* __restrict__ wgt,
    const float* __restrict__ mask,
    float* __restrict__ dst_f32,
    signed char* __restrict__ dst8, float* __restrict__ dst_scale,
    int n, int apply_logmap)
{
    __shared__ int   eoffS[TMG][DEG];        // element offsets into Z8
    __shared__ float ewgtS[TMG][DEG];        // |w| * src row scale
    __shared__ float msh[TMG];

    const int row0 = blockIdx.x * TMG;
    const int tid  = threadIdx.x;

    // ---- phase 0: stage edges (1 dword adj + 1 dword wgt + 1 scattered scale) ----
    {
        const int nd = tid >> 4, eg = tid & 15;
        int   av = adj[(size_t)(row0 + nd) * DEG + eg];
        float wv = wgt[(size_t)(row0 + nd) * DEG + eg];
        const int sel = (wv > 0.f) ? 0 : 1;          // pos -> Zp, else Zn
        const float* sp = sel ? zscN : zscP;
        eoffS[nd][eg] = av * DD + sel * (n * DD);
        ewgtS[nd][eg] = fabsf(wv) * sp[av];          // wv==0 -> 0 (no contribution)
        if (tid < TMG) msh[tid] = mask[row0 + tid];
    }
    __syncthreads();

    // ---- phase 1: 8 x 16B int8 gathers/lane-group (R7 geometry, single acc) ----
    const int l64  = tid & 63;
    const int node = (tid >> 6) * 4 + (l64 >> 4);   // 4 nodes per wave
    const int e    = (l64 >> 3) & 1;                // edge parity
    const int g    = l64 & 7;                       // 16-byte column group

    int   offl[8];
    float wl[8];
    #pragma unroll
    for (int j = 0; j < 8; ++j) {
        offl[j] = eoffS[node][2 * j + e];
        wl[j]   = ewgtS[node][2 * j + e];
    }

    float a[16];
    #pragma unroll
    for (int c = 0; c < 16; ++c) a[c] = 0.f;
    const signed char* __restrict__ srcg = Z8 + g * 16;
    #pragma unroll
    for (int j = 0; j < 8; ++j) {
        c16v v = *(const c16v*)(srcg + (size_t)offl[j]);
        float wj = wl[j];
        #pragma unroll
        for (int c = 0; c < 16; ++c) a[c] += wj * (float)v[c];
    }
    // parity merge (R7-verified): keep own half, send the opposite half
    float f[8];
    #pragma unroll
    for (int c = 0; c < 8; ++c) {
        float own  = e ? a[8 + c] : a[c];
        float send = e ? a[c]     : a[8 + c];
        f[c] = own + __shfl_xor(send, 8);
    }

    // ---- epilogue, fully in-register (16-lane group = one node's 128 cols) ----
    const int   row = row0 + node;
    const float m   = msh[node];
    float t[8];
    float p = 0.f;
    #pragma unroll
    for (int c = 0; c < 8; ++c) { float cv = f[c] * m; t[c] = cv; p += cv * cv; }
    p += __shfl_xor(p, 1); p += __shfl_xor(p, 2);
    p += __shfl_xor(p, 4); p += __shfl_xor(p, 8);
    float nc = fmaxf(sqrtf(p), EPSV);
    float sc = fast_tanh_over(nc);
    float s2 = 0.f;
    #pragma unroll
    for (int c = 0; c < 8; ++c) {
        t[c] = fmaxf(t[c] * sc * m, 0.f) * m;        // expmap*m, relu, *m
        s2 += t[c] * t[c];
    }

    if (apply_logmap) {
        s2 += __shfl_xor(s2, 1); s2 += __shfl_xor(s2, 2);
        s2 += __shfl_xor(s2, 4); s2 += __shfl_xor(s2, 8);
        float nc2 = fminf(fmaxf(sqrtf(s2), EPSV), 1.f - EPSV);
        float ff  = fast_atanh_over(nc2) * m * m;    // store logmap*mask^2
        float y[8], rmax = 0.f;
        #pragma unroll
        for (int c = 0; c < 8; ++c) { y[c] = t[c] * ff; rmax = fmaxf(rmax, fabsf(y[c])); }
        rmax = fmaxf(rmax, __shfl_xor(rmax, 1));
        rmax = fmaxf(rmax, __shfl_xor(rmax, 2));
        rmax = fmaxf(rmax, __shfl_xor(rmax, 4));
        rmax = fmaxf(rmax, __shfl_xor(rmax, 8));
        float qs = __fdividef(127.f, fmaxf(rmax, 1e-20f));
        int q[8];
        #pragma unroll
        for (int c = 0; c < 8; ++c) q[c] = __float2int_rn(y[c] * qs);
        unsigned lo = (q[0]&255) | ((q[1]&255)<<8) | ((q[2]&255)<<16) | ((unsigned)(q[3]&255)<<24);
        unsigned hi = (q[4]&255) | ((q[5]&255)<<8) | ((q[6]&255)<<16) | ((unsigned)(q[7]&255)<<24);
        *(uint2*)(dst8 + (size_t)row * DD + g * 16 + e * 8) = make_uint2(lo, hi);
        if ((l64 & 15) == 0) dst_scale[row] = rmax * (1.f / 127.f);
    } else {
        float* drow = dst_f32 + (size_t)row * DD + g * 16 + e * 8;
        ((float4*)drow)[0] = make_float4(t[0], t[1], t[2], t[3]);
        ((float4*)drow)[1] = make_float4(t[4], t[5], t[6], t[7]);
    }
}

extern "C" void kernel_launch(void* const* d_in, const int* in_sizes, int n_in,
                              void* d_out, int out_size, void* d_ws, size_t ws_size,
                              hipStream_t stream)
{
    const float* node_repr = (const float*)d_in[0];
    const int*   adj       = (const int*)  d_in[1];
    const float* weight    = (const float*)d_in[2];
    const float* mask      = (const float*)d_in[3];
    const float* W_pos     = (const float*)d_in[4];   // [L,128,128]
    const float* W_neg     = (const float*)d_in[5];

    const int n = in_sizes[0] / DD;                   // 50000

    // workspace (~20 MB): Z8[2][n][128] | y8 | zscP | zscN | ysc | WT
    signed char* Z8   = (signed char*)d_ws;                    // 2*n*128 B
    signed char* y8   = Z8 + (size_t)2 * n * DD;               // n*128 B
    float*       zscP = (float*)(y8 + (size_t)n * DD);         // n f32
    float*       zscN = zscP + n;                              // n f32
    float*       ysc  = zscN + n;                              // n f32
    _Float16*    WT   = (_Float16*)(ysc + n);                  // 4*128*128 f16

    prepW<<<32, 256, 0, stream>>>(W_pos, W_neg, WT);

    dim3 zgrid((n + TMZ - 1) / TMZ);                           // 1563 blocks
    dim3 ggrid((n + TMG - 1) / TMG);                           // 3125 blocks

    // layer 0: Z = (x*m^2) @ W0 (dense, absorbs cold x) -> gather -> y8/ysc
    z_gemm<<<zgrid, 256, 0, stream>>>(node_repr, nullptr, nullptr, mask,
                                      WT + 0 * DD * DD, WT + 1 * DD * DD,
                                      Z8, zscP, zscN, n, 1);
    gather_ep<<<ggrid, 256, 0, stream>>>(Z8, zscP, zscN, adj, weight, mask,
                                         nullptr, y8, ysc, n, 1);
    // layer 1: Z = y @ W1 (dense, warm) -> gather -> f32 output
    z_gemm<<<zgrid, 256, 0, stream>>>(nullptr, y8, ysc, mask,
                                      WT + 2 * DD * DD, WT + 3 * DD * DD,
                                      Z8, zscP, zscN, n, 0);
    gather_ep<<<ggrid, 256, 0, stream>>>(Z8, zscP, zscN, adj, weight, mask,
                                         (float*)d_out, nullptr, nullptr, n, 0);
}

// Round 15
// 180.378 us; speedup vs baseline: 1.2488x; 1.0620x over previous
//
#include <hip/hip_runtime.h>
#include <math.h>

#define DD 128          // embed dim
#define DEG 16          // neighbors
#define TMG 16          // gather tile (3125 blocks exact)
#define TMZ 32          // z-gemm rows per block (1563 blocks)
#define LDST 136        // LDS row stride in f16
#define EPSV 1e-5f

typedef _Float16 half8_t __attribute__((ext_vector_type(8)));
typedef float    f32x4   __attribute__((ext_vector_type(4)));
typedef signed char c16v __attribute__((ext_vector_type(16)));

// fast tanh(n)/n, n >= EPSV.
__device__ __forceinline__ float fast_tanh_over(float n) {
    float e  = __expf(2.f * n);
    float th = 1.f - __fdividef(2.f, e + 1.f);
    return __fdividef(th, n);
}
// fast atanh(n)/n, n in [EPSV, 1-EPSV]
__device__ __forceinline__ float fast_atanh_over(float n) {
    float r = 0.5f * __logf(__fdividef(1.f + n, 1.f - n));
    return __fdividef(r, n);
}

// ---- prepW: W->f16 transpose (verified layout: WT[n][k]) ----
__global__ void prepW(const float* __restrict__ Wp, const float* __restrict__ Wn,
                      _Float16* __restrict__ WT)
{
    int bid   = blockIdx.x;            // 0..31
    int mat   = bid >> 3;              // 0..3: [l0p, l0n, l1p, l1n]
    int chunk = bid & 7;
    int l = mat >> 1, rel = mat & 1;
    const float* __restrict__ src = (rel ? Wn : Wp) + (size_t)l * DD * DD;
    _Float16* __restrict__ dst = WT + (size_t)mat * DD * DD;
    for (int o = chunk * 2048 + threadIdx.x; o < chunk * 2048 + 2048; o += 256) {
        int nn = o >> 7, kk = o & 127;
        dst[o] = (_Float16)src[kk * DD + nn];   // WT[n][k] (transposed)
    }
}

// ---- z_gemm0: dense Z0^rel = (x*m^2) @ W0^rel, int8 per-row out (R14 body,
// layer0-specialized). Absorbs the cold-x read.
__global__ __launch_bounds__(256, 2) void z_gemm0(
    const float* __restrict__ xf32, const float* __restrict__ mask,
    const _Float16* __restrict__ WTp, const _Float16* __restrict__ WTn,
    signed char* __restrict__ Z8, float* __restrict__ zscP,
    float* __restrict__ zscN, int n)
{
    __shared__ __align__(16) _Float16 At[TMZ][LDST];    // 8.7 KB

    const int row0 = blockIdx.x * TMZ;
    const int tid  = threadIdx.x;
    {
        const int ar   = tid >> 3;
        const int ac   = (tid & 7) * 16;
        const int rowg = row0 + ar;
        _Float16 hv[16];
        if (rowg < n) {
            float m = mask[rowg]; float m2 = m * m;
            const float4* xp = (const float4*)(xf32 + (size_t)rowg * DD + ac);
            #pragma unroll
            for (int q4 = 0; q4 < 4; ++q4) {
                float4 v = xp[q4];
                hv[q4*4+0] = (_Float16)(v.x*m2); hv[q4*4+1] = (_Float16)(v.y*m2);
                hv[q4*4+2] = (_Float16)(v.z*m2); hv[q4*4+3] = (_Float16)(v.w*m2);
            }
        } else {
            #pragma unroll
            for (int c = 0; c < 16; ++c) hv[c] = (_Float16)0.f;
        }
        *(half8_t*)&At[ar][ac]     = *(half8_t*)&hv[0];
        *(half8_t*)&At[ar][ac + 8] = *(half8_t*)&hv[8];
    }
    __syncthreads();

    const int w    = tid >> 6;       // wave 0..3
    const int mt   = w >> 1;         // row half 0/1
    const int rel  = w & 1;          // 0=P, 1=N
    const int l64  = tid & 63;
    const int l15  = l64 & 15;
    const int quad = l64 >> 4;

    half8_t aF[4];
    #pragma unroll
    for (int kb = 0; kb < 4; ++kb)
        aF[kb] = *(const half8_t*)&At[mt * 16 + l15][kb * 32 + quad * 8];

    const _Float16* __restrict__ WT = rel ? WTn : WTp;
    f32x4 acc[8];
    #pragma unroll
    for (int nb = 0; nb < 8; ++nb) acc[nb] = (f32x4){0.f, 0.f, 0.f, 0.f};
    #pragma unroll
    for (int nb = 0; nb < 8; ++nb) {
        const _Float16* bp = WT + (size_t)(nb * 16 + l15) * DD + quad * 8;
        #pragma unroll
        for (int kb = 0; kb < 4; ++kb)
            acc[nb] = __builtin_amdgcn_mfma_f32_16x16x32_f16(
                aF[kb], *(const half8_t*)(bp + kb * 32), acc[nb], 0, 0, 0);
    }

    signed char* __restrict__ zb  = Z8 + (size_t)rel * n * DD;
    float*       __restrict__ zsc = rel ? zscN : zscP;
    #pragma unroll
    for (int r = 0; r < 4; ++r) {
        const int rowg = row0 + mt * 16 + quad * 4 + r;
        float mx = 0.f;
        #pragma unroll
        for (int nb = 0; nb < 8; ++nb) mx = fmaxf(mx, fabsf(acc[nb][r]));
        mx = fmaxf(mx, __shfl_xor(mx, 1));
        mx = fmaxf(mx, __shfl_xor(mx, 2));
        mx = fmaxf(mx, __shfl_xor(mx, 4));
        mx = fmaxf(mx, __shfl_xor(mx, 8));
        if (rowg < n) {
            float qs = __fdividef(127.f, fmaxf(mx, 1e-20f));
            signed char* zr = zb + (size_t)rowg * DD + l15;
            #pragma unroll
            for (int nb = 0; nb < 8; ++nb)
                zr[nb * 16] = (signed char)__float2int_rn(acc[nb][r] * qs);
            if (l15 == 0) zsc[rowg] = mx * (1.f / 127.f);
        }
    }
}

// ---- fused_mid: gather(Z0) -> in-reg epilogue -> y f16 (LDS ONLY, never in
// memory) -> GEMM W1 -> Z1 int8. R15 fusion: z_gemm L1 row r needs only y row
// r, and the gather block produces exactly its 16 y rows -> block-local fuse.
// Deletes one dispatch + the full y8/ysc roundtrip + one quant stage.
__global__ __launch_bounds__(256, 2) void fused_mid(
    const signed char* __restrict__ Z0,
    const float* __restrict__ zsc0P, const float* __restrict__ zsc0N,
    const int*   __restrict__ adj, const float* __restrict__ wgt,
    const float* __restrict__ mask,
    const _Float16* __restrict__ WT1p, const _Float16* __restrict__ WT1n,
    signed char* __restrict__ Z1,
    float* __restrict__ zsc1P, float* __restrict__ zsc1N, int n)
{
    __shared__ int   eoffS[TMG][DEG];
    __shared__ float ewgtS[TMG][DEG];
    __shared__ float msh[TMG];
    __shared__ __align__(16) _Float16 yt[TMG][LDST];    // 4.25 KB
    __shared__ float partQ[2][2][TMG];                   // [rel][colhalf][row]

    const int row0 = blockIdx.x * TMG;
    const int tid  = threadIdx.x;

    // ---- phase 0: stage edges (sel by weight sign; |w|*zsc0 folded) ----
    {
        const int nd = tid >> 4, eg = tid & 15;
        int   av = adj[(size_t)(row0 + nd) * DEG + eg];
        float wv = wgt[(size_t)(row0 + nd) * DEG + eg];
        const int sel = (wv > 0.f) ? 0 : 1;
        const float* sp = sel ? zsc0N : zsc0P;
        eoffS[nd][eg] = av * DD + sel * (n * DD);
        ewgtS[nd][eg] = fabsf(wv) * sp[av];
        if (tid < TMG) msh[tid] = mask[row0 + tid];
    }
    __syncthreads();

    // ---- phase 1: gather + parity merge + in-register epilogue -> y ----
    const int l64  = tid & 63;
    const int node = (tid >> 6) * 4 + (l64 >> 4);
    const int e    = (l64 >> 3) & 1;
    const int g    = l64 & 7;

    int   offl[8];
    float wl[8];
    #pragma unroll
    for (int j = 0; j < 8; ++j) {
        offl[j] = eoffS[node][2 * j + e];
        wl[j]   = ewgtS[node][2 * j + e];
    }

    float a[16];
    #pragma unroll
    for (int c = 0; c < 16; ++c) a[c] = 0.f;
    const signed char* __restrict__ srcg = Z0 + g * 16;
    #pragma unroll
    for (int j = 0; j < 8; ++j) {
        c16v v = *(const c16v*)(srcg + (size_t)offl[j]);
        float wj = wl[j];
        #pragma unroll
        for (int c = 0; c < 16; ++c) a[c] += wj * (float)v[c];
    }
    float f[8];
    #pragma unroll
    for (int c = 0; c < 8; ++c) {                 // R7-verified parity merge
        float own  = e ? a[8 + c] : a[c];
        float send = e ? a[c]     : a[8 + c];
        f[c] = own + __shfl_xor(send, 8);
    }

    const float m = msh[node];
    float t[8];
    float p = 0.f;
    #pragma unroll
    for (int c = 0; c < 8; ++c) { float cv = f[c] * m; t[c] = cv; p += cv * cv; }
    p += __shfl_xor(p, 1); p += __shfl_xor(p, 2);
    p += __shfl_xor(p, 4); p += __shfl_xor(p, 8);
    float nc = fmaxf(sqrtf(p), EPSV);
    float sc = fast_tanh_over(nc);
    float s2 = 0.f;
    #pragma unroll
    for (int c = 0; c < 8; ++c) {
        t[c] = fmaxf(t[c] * sc * m, 0.f) * m;     // expmap*m, relu, *m
        s2 += t[c] * t[c];
    }
    s2 += __shfl_xor(s2, 1); s2 += __shfl_xor(s2, 2);
    s2 += __shfl_xor(s2, 4); s2 += __shfl_xor(s2, 8);
    float nc2 = fminf(fmaxf(sqrtf(s2), EPSV), 1.f - EPSV);
    float ff  = fast_atanh_over(nc2) * m * m;     // y = logmap(x)*mask^2
    half8_t hy;
    #pragma unroll
    for (int c = 0; c < 8; ++c) hy[c] = (_Float16)(t[c] * ff);
    *(half8_t*)&yt[node][g * 16 + e * 8] = hy;
    __syncthreads();

    // ---- phase 2: GEMM y @ W1. 4 waves = 2 rels x 2 col-halves ----
    const int w    = tid >> 6;
    const int rel  = w >> 1;         // 0=P, 1=N
    const int ch   = w & 1;          // cols ch*64 .. ch*64+63
    const int l15  = l64 & 15;
    const int quad = l64 >> 4;

    half8_t aF[4];
    #pragma unroll
    for (int kb = 0; kb < 4; ++kb)
        aF[kb] = *(const half8_t*)&yt[l15][kb * 32 + quad * 8];

    const _Float16* __restrict__ WT = rel ? WT1n : WT1p;
    f32x4 acc[4];
    #pragma unroll
    for (int nb = 0; nb < 4; ++nb) acc[nb] = (f32x4){0.f, 0.f, 0.f, 0.f};
    #pragma unroll
    for (int nb = 0; nb < 4; ++nb) {
        const _Float16* bp = WT + (size_t)((ch * 4 + nb) * 16 + l15) * DD + quad * 8;
        #pragma unroll
        for (int kb = 0; kb < 4; ++kb)
            acc[nb] = __builtin_amdgcn_mfma_f32_16x16x32_f16(
                aF[kb], *(const half8_t*)(bp + kb * 32), acc[nb], 0, 0, 0);
    }

    // ---- phase 3: per-row int8 quant of Z1 (one partials barrier) ----
    #pragma unroll
    for (int r = 0; r < 4; ++r) {
        float mx = 0.f;
        #pragma unroll
        for (int nb = 0; nb < 4; ++nb) mx = fmaxf(mx, fabsf(acc[nb][r]));
        mx = fmaxf(mx, __shfl_xor(mx, 1));
        mx = fmaxf(mx, __shfl_xor(mx, 2));
        mx = fmaxf(mx, __shfl_xor(mx, 4));
        mx = fmaxf(mx, __shfl_xor(mx, 8));
        if (l15 == 0) partQ[rel][ch][quad * 4 + r] = mx;
    }
    __syncthreads();

    signed char* __restrict__ zb  = Z1 + (size_t)rel * n * DD;
    float*       __restrict__ zsc = rel ? zsc1N : zsc1P;
    #pragma unroll
    for (int r = 0; r < 4; ++r) {
        const int rl   = quad * 4 + r;
        const int rowg = row0 + rl;
        float rmax = fmaxf(partQ[rel][0][rl], partQ[rel][1][rl]);
        float qs = __fdividef(127.f, fmaxf(rmax, 1e-20f));
        signed char* zr = zb + (size_t)rowg * DD + ch * 64 + l15;
        #pragma unroll
        for (int nb = 0; nb < 4; ++nb)
            zr[nb * 16] = (signed char)__float2int_rn(acc[nb][r] * qs);
        if (ch == 0 && l15 == 0) zsc[rowg] = rmax * (1.f / 127.f);
    }
}

// ---- gather_final: gather(Z1) + epilogue -> f32 output (R14 body, no-logmap) ----
__global__ __launch_bounds__(256, 2) void gather_final(
    const signed char* __restrict__ Z1,
    const float* __restrict__ zsc1P, const float* __restrict__ zsc1N,
    const int*   __restrict__ adj, const float* __restrict__ wgt,
    const float* __restrict__ mask,
    float* __restrict__ dst_f32, int n)
{
    __shared__ int   eoffS[TMG][DEG];
    __shared__ float ewgtS[TMG][DEG];
    __shared__ float msh[TMG];

    const int row0 = blockIdx.x * TMG;
    const int tid  = threadIdx.x;
    {
        const int nd = tid >> 4, eg = tid & 15;
        int   av = adj[(size_t)(row0 + nd) * DEG + eg];
        float wv = wgt[(size_t)(row0 + nd) * DEG + eg];
        const int sel = (wv > 0.f) ? 0 : 1;
        const float* sp = sel ? zsc1N : zsc1P;
        eoffS[nd][eg] = av * DD + sel * (n * DD);
        ewgtS[nd][eg] = fabsf(wv) * sp[av];
        if (tid < TMG) msh[tid] = mask[row0 + tid];
    }
    __syncthreads();

    const int l64  = tid & 63;
    const int node = (tid >> 6) * 4 + (l64 >> 4);
    const int e    = (l64 >> 3) & 1;
    const int g    = l64 & 7;

    int   offl[8];
    float wl[8];
    #pragma unroll
    for (int j = 0; j < 8; ++j) {
        offl[j] = eoffS[node][2 * j + e];
        wl[j]   = ewgtS[node][2 * j + e];
    }

    float a[16];
    #pragma unroll
    for (int c = 0; c < 16; ++c) a[c] = 0.f;
    const signed char* __restrict__ srcg = Z1 + g * 16;
    #pragma unroll
    for (int j = 0; j < 8; ++j) {
        c16v v = *(const c16v*)(srcg + (size_t)offl[j]);
        float wj = wl[j];
        #pragma unroll
        for (int c = 0; c < 16; ++c) a[c] += wj * (float)v[c];
    }
    float f[8];
    #pragma unroll
    for (int c = 0; c < 8; ++c) {
        float own  = e ? a[8 + c] : a[c];
        float send = e ? a[c]     : a[8 + c];
        f[c] = own + __shfl_xor(send, 8);
    }

    const int   row = row0 + node;
    const float m   = msh[node];
    float t[8];
    float p = 0.f;
    #pragma unroll
    for (int c = 0; c < 8; ++c) { float cv = f[c] * m; t[c] = cv; p += cv * cv; }
    p += __shfl_xor(p, 1); p += __shfl_xor(p, 2);
    p += __shfl_xor(p, 4); p += __shfl_xor(p, 8);
    float nc = fmaxf(sqrtf(p), EPSV);
    float sc = fast_tanh_over(nc);
    #pragma unroll
    for (int c = 0; c < 8; ++c)
        t[c] = fmaxf(t[c] * sc * m, 0.f) * m;

    float* drow = dst_f32 + (size_t)row * DD + g * 16 + e * 8;
    ((float4*)drow)[0] = make_float4(t[0], t[1], t[2], t[3]);
    ((float4*)drow)[1] = make_float4(t[4], t[5], t[6], t[7]);
}

extern "C" void kernel_launch(void* const* d_in, const int* in_sizes, int n_in,
                              void* d_out, int out_size, void* d_ws, size_t ws_size,
                              hipStream_t stream)
{
    const float* node_repr = (const float*)d_in[0];
    const int*   adj       = (const int*)  d_in[1];
    const float* weight    = (const float*)d_in[2];
    const float* mask      = (const float*)d_in[3];
    const float* W_pos     = (const float*)d_in[4];   // [L,128,128]
    const float* W_neg     = (const float*)d_in[5];

    const int n = in_sizes[0] / DD;                   // 50000

    // workspace (~26.5 MB): Z0[2][n][128] | Z1[2][n][128] | scales | WT
    signed char* Z0    = (signed char*)d_ws;                   // 2*n*128 B
    signed char* Z1    = Z0 + (size_t)2 * n * DD;              // 2*n*128 B
    float*       zsc0P = (float*)(Z1 + (size_t)2 * n * DD);    // n f32 each
    float*       zsc0N = zsc0P + n;
    float*       zsc1P = zsc0N + n;
    float*       zsc1N = zsc1P + n;
    _Float16*    WT    = (_Float16*)(zsc1N + n);               // 4*128*128 f16

    prepW<<<32, 256, 0, stream>>>(W_pos, W_neg, WT);

    dim3 zgrid((n + TMZ - 1) / TMZ);                           // 1563 blocks
    dim3 ggrid((n + TMG - 1) / TMG);                           // 3125 blocks

    // K1: Z0 = (x*m^2) @ W0 (dense; absorbs cold x)
    z_gemm0<<<zgrid, 256, 0, stream>>>(node_repr, mask,
                                       WT + 0 * DD * DD, WT + 1 * DD * DD,
                                       Z0, zsc0P, zsc0N, n);
    // K2: gather Z0 -> y (LDS-only f16) -> GEMM W1 -> Z1
    fused_mid<<<ggrid, 256, 0, stream>>>(Z0, zsc0P, zsc0N, adj, weight, mask,
                                         WT + 2 * DD * DD, WT + 3 * DD * DD,
                                         Z1, zsc1P, zsc1N, n);
    // K3: gather Z1 -> epilogue -> f32 output
    gather_final<<<ggrid, 256, 0, stream>>>(Z1, zsc1P, zsc1N, adj, weight, mask,
                                            (float*)d_out, n);
}